// Round 18
// baseline (1932.605 us; speedup 1.0000x reference)
//
#include <hip/hip_runtime.h>

// FDTD rollout — register-resident wave-per-tile structure with launch guards.
// Tile 16x16, region 48x48, ONE WAVE PER TILE, whole region in registers
// (lane = column, 48 rows/lane; A=cur, B=prev, dcv=1e-4*c; rr = dcv*dcv).
// Vertical neighbors = registers; horizontal = DPP. Zero LDS / barriers /
// waits inside a 16-step group.
// Packing: 256 blocks x 256 threads (4 independent waves/block, tile =
// blockIdx*4+w). __launch_bounds__(256,2) caps VGPR at 256 -> cooperative
// capacity >= 512 blocks. Host verifies occupancy + launch return code and
// falls back to 16 plain launches (one group each) if cooperative fails.
// Group boundaries (coop path): wave-level flag sync — drain own stores
// (vmcnt0), publish flags[tile] (agent scope), spin on 8 neighbor tiles,
// reload all state outside the kept 16x16 tile.

#define HH 512
#define WW 512
#define HW (HH * WW)
#define TILE 16
#define TS 16
#define REG 48    // region rows (= useful cols; lanes 48..63 stay zero)
#define PHC ((float)(2.0 * 3.1415926 * 100.0))

#if __has_builtin(__builtin_amdgcn_update_dpp)
__device__ __forceinline__ float nbrL(float x) {   // value from lane-1 (left)
    int i = __builtin_bit_cast(int, x);
    i = __builtin_amdgcn_update_dpp(i, i, 0x138, 0xf, 0xf, false); // wave_shr:1
    return __builtin_bit_cast(float, i);
}
__device__ __forceinline__ float nbrR(float x) {   // value from lane+1 (right)
    int i = __builtin_bit_cast(int, x);
    i = __builtin_amdgcn_update_dpp(i, i, 0x130, 0xf, 0xf, false); // wave_shl:1
    return __builtin_bit_cast(float, i);
}
#else
__device__ __forceinline__ float nbrL(float x) { return __shfl_up(x, 1, 64); }
__device__ __forceinline__ float nbrR(float x) { return __shfl_down(x, 1, 64); }
#endif

__global__ void fdtd_zero_flags(int* f) { f[blockIdx.x * 256 + threadIdx.x] = 0; }

// One step: X = cur, Y = prev on entry; Y = new frame on exit (in place).
// CE adds the column-boundary override pass (tx-edge tiles only).
template<bool CE>
__device__ __forceinline__ void fstep(
    float (&X)[REG], float (&Y)[REG], const float (&dcv)[REG],
    unsigned long long m0, unsigned long long m511, bool hasRow,
    bool isCB, bool useR,
    bool whs, unsigned long long smask, float srcv,
    bool lstore, float* op)
{
    #pragma unroll
    for (int j = 0; j < REG; ++j) {
        const float c = X[j];
        const float u = (j == 0)       ? c : X[j - 1];   // j=0 sealed/garbage
        const float d = (j == REG - 1) ? c : X[j + 1];   // j=47 sealed/garbage
        const float l = nbrL(c);
        const float r = nbrR(c);
        const float lap = ((u + d) + (l + r)) - 4.f * c;
        Y[j] = 2.f * c - Y[j] + dcv[j] * (dcv[j] * lap); // rr = dcv^2
    }
    if (whs) {                                  // source injection
        #pragma unroll
        for (int j = 0; j < REG; ++j)
            if ((smask >> j) & 1ull) Y[j] = srcv;
    }
    // precedence (last wins): row0 < col0 < col511 < row511
    if (CE) {
        #pragma unroll
        for (int j = 0; j < REG; ++j) {
            const float c = X[j];
            if (j < REG - 1) if ((m0 >> j) & 1ull)
                Y[j] = c - dcv[j] * (c - X[j + 1]);
            const float nb = useR ? nbrR(c) : nbrL(c);  // tile-uniform choice
            const float t  = c - dcv[j] * (c - nb);
            Y[j] = isCB ? t : Y[j];
            if (j > 0) if ((m511 >> j) & 1ull)
                Y[j] = c - dcv[j] * (c - X[j - 1]);
        }
    } else if (hasRow) {                        // row-edge only
        #pragma unroll
        for (int j = 0; j < REG; ++j) {
            if (j < REG - 1) if ((m0 >> j) & 1ull)
                Y[j] = X[j] - dcv[j] * (X[j] - X[j + 1]);
            if (j > 0) if ((m511 >> j) & 1ull)
                Y[j] = X[j] - dcv[j] * (X[j] - X[j - 1]);
        }
    }
    if (lstore) {                               // tile = rows/lanes [16,32)
        #pragma unroll
        for (int i = 0; i < 16; ++i)
            __hip_atomic_store(op + i * WW, Y[16 + i], __ATOMIC_RELAXED,
                               __HIP_MEMORY_SCOPE_AGENT);
    }
}

__global__ __launch_bounds__(256, 2)
void fdtd_rt(const float* __restrict__ in_out,
             const float* __restrict__ cmap,
             const int* __restrict__ locx,
             const int* __restrict__ locy,
             const int* __restrict__ pb,
             const int* __restrict__ pid2,
             float* __restrict__ out,
             int steps, int t0b, int t0e, int* __restrict__ flags)
{
    const int lane = threadIdx.x & 63;       // column within region
    const int w    = threadIdx.x >> 6;       // wave 0..3
    const int t    = blockIdx.x * 4 + w;     // tile id 0..1023
    const int tx   = t & 31;
    const int ty   = t >> 5;
    const int gx0  = tx * TILE - 16;
    const int gy0  = ty * TILE - 16;
    const int gc   = gx0 + lane;

    const int lx0 = locx[0], ly0 = locy[0];
    const int lx1 = locx[1], ly1 = locy[1];
    const int lx2 = locx[2], ly2 = locy[2];
    const int Bn  = pb[0] * pid2[0];

    float A[REG], B[REG], dcv[REG];
    unsigned long long smask = 0;
    const bool colOK = (lane < REG) & (gc >= 0) & (gc < WW);

    // ---- initial state: frames t0b, t0b+1 (in_out for t0b==0, else planes)
    const float* c0 = (t0b == 0) ? (in_out + HW)
                                 : (out + (size_t)(t0b - 1) * (size_t)HW);
    const float* p0 = (t0b == 0) ? in_out
                                 : (out + (size_t)(t0b - 2) * (size_t)HW);
    #pragma unroll
    for (int j = 0; j < REG; ++j) {
        const int gr = gy0 + j;
        float c = 0.f, ce2 = 0.f, pp = 0.f;
        if (colOK && gr >= 0 && gr < HH) {
            const int gi = gr * WW + gc;
            c   = cmap[gi];
            ce2 = c0[gi];
            pp  = p0[gi];
        }
        A[j] = ce2; B[j] = pp;
        dcv[j] = 1.0e-4f * c;
        if ((gr == lx0 && gc == ly0) || (gr == lx1 && gc == ly1) ||
            (gr == lx2 && gc == ly2)) smask |= (1ull << j);
    }
    const bool whs = __any((int)(smask != 0ull));

    // physical-row masks (wave-uniform)
    unsigned long long m0 = 0, m511 = 0;
    { const int j0 = -gy0;      if (j0 >= 0 && j0 < REG) m0   = 1ull << j0; }
    { const int j5 = 511 - gy0; if (j5 >= 0 && j5 < REG) m511 = 1ull << j5; }
    const bool hasRow = (m0 | m511) != 0ull;
    const bool isCB   = (gc == 0) | (gc == WW - 1);
    const bool useR   = (tx <= 1);
    const bool ce     = (tx <= 1) | (tx >= 30);
    const bool lstore = (lane >= 16) & (lane < 32);
    const int  rowOffT = (gy0 + 16) * WW + gc;

    for (int t0 = t0b; t0 < t0e; t0 += TS) {
        const int nk = (t0e - t0 < TS) ? (t0e - t0) : TS;

        if (t0 > t0b) {
            // ---- group boundary (coop path only): wave-level flag sync ----
            asm volatile("s_waitcnt vmcnt(0)" ::: "memory"); // my stores @ LLC
            if (lane == 0)
                __hip_atomic_store(&flags[t], t0,
                                   __ATOMIC_RELAXED, __HIP_MEMORY_SCOPE_AGENT);
            if (lane < 8) {
                const int dy[8] = {-1,-1,-1, 0, 0, 1, 1, 1};
                const int dx[8] = {-1, 0, 1,-1, 1,-1, 0, 1};
                const int nty = ty + dy[lane];
                const int ntx = tx + dx[lane];
                if (nty >= 0 && nty < 32 && ntx >= 0 && ntx < 32) {
                    const int nb = (nty << 5) | ntx;
                    while (__hip_atomic_load(&flags[nb], __ATOMIC_RELAXED,
                                             __HIP_MEMORY_SCOPE_AGENT) < t0)
                        __builtin_amdgcn_s_sleep(2);
                }
            }
            asm volatile("" ::: "memory");   // keep reloads after the spin
            // reload everything outside the kept tile (rows/lanes [16,32))
            const float* cF = out + (size_t)(t0 - 1) * (size_t)HW;
            const float* pF = cF - HW;
            #pragma unroll
            for (int j = 0; j < REG; ++j) {
                const bool vrow = (j >= 16) & (j < 32);
                if (!(vrow & lstore)) {
                    const int gr = gy0 + j;
                    float ce2 = 0.f, pp2 = 0.f;
                    if (colOK && gr >= 0 && gr < HH) {
                        const int gi = gr * WW + gc;
                        ce2 = __hip_atomic_load(cF + gi, __ATOMIC_RELAXED,
                                                __HIP_MEMORY_SCOPE_AGENT);
                        pp2 = __hip_atomic_load(pF + gi, __ATOMIC_RELAXED,
                                                __HIP_MEMORY_SCOPE_AGENT);
                    }
                    A[j] = ce2; B[j] = pp2;
                }
            }
        }

        float* op = out + (size_t)t0 * (size_t)HW + rowOffT;
        if (!ce) {
            for (int k = 1; k + 1 <= nk; k += 2) {
                float s1 = 0.f, s2 = 0.f;
                if (whs) {
                    s1 = 1500.0f * __sinf(PHC * (float)(Bn + t0 + k + 1) * 1.0e-4f);
                    s2 = 1500.0f * __sinf(PHC * (float)(Bn + t0 + k + 2) * 1.0e-4f);
                }
                fstep<false>(A, B, dcv, m0, m511, hasRow, isCB, useR,
                             whs, smask, s1, lstore, op);
                op += HW;
                fstep<false>(B, A, dcv, m0, m511, hasRow, isCB, useR,
                             whs, smask, s2, lstore, op);
                op += HW;
            }
            if (nk & 1) {
                float s1 = 0.f;
                if (whs)
                    s1 = 1500.0f * __sinf(PHC * (float)(Bn + t0 + nk + 1) * 1.0e-4f);
                fstep<false>(A, B, dcv, m0, m511, hasRow, isCB, useR,
                             whs, smask, s1, lstore, op);
                #pragma unroll
                for (int j = 0; j < REG; ++j) {
                    const float tt = A[j]; A[j] = B[j]; B[j] = tt;
                }
            }
        } else {
            for (int k = 1; k + 1 <= nk; k += 2) {
                float s1 = 0.f, s2 = 0.f;
                if (whs) {
                    s1 = 1500.0f * __sinf(PHC * (float)(Bn + t0 + k + 1) * 1.0e-4f);
                    s2 = 1500.0f * __sinf(PHC * (float)(Bn + t0 + k + 2) * 1.0e-4f);
                }
                fstep<true>(A, B, dcv, m0, m511, hasRow, isCB, useR,
                            whs, smask, s1, lstore, op);
                op += HW;
                fstep<true>(B, A, dcv, m0, m511, hasRow, isCB, useR,
                            whs, smask, s2, lstore, op);
                op += HW;
            }
            if (nk & 1) {
                float s1 = 0.f;
                if (whs)
                    s1 = 1500.0f * __sinf(PHC * (float)(Bn + t0 + nk + 1) * 1.0e-4f);
                fstep<true>(A, B, dcv, m0, m511, hasRow, isCB, useR,
                            whs, smask, s1, lstore, op);
                #pragma unroll
                for (int j = 0; j < REG; ++j) {
                    const float tt = A[j]; A[j] = B[j]; B[j] = tt;
                }
            }
        }
    }
}

extern "C" void kernel_launch(void* const* d_in, const int* in_sizes, int n_in,
                              void* d_out, int out_size, void* d_ws, size_t ws_size,
                              hipStream_t stream) {
    const float* in_out = (const float*)d_in[0];   // [steps+2, 1, 512, 512]
    const float* cmap   = (const float*)d_in[1];   // [1,1,512,512]
    const int*   locx   = (const int*)d_in[2];
    const int*   locy   = (const int*)d_in[3];
    const int*   pb     = (const int*)d_in[4];     // bsize1
    const int*   pid2   = (const int*)d_in[5];     // id2
    float*       outp   = (float*)d_out;
    int*         flags  = (int*)d_ws;              // 1024 tile progress flags

    int steps = out_size / HW;

    // ---- deterministic launch-capability check ----
    int maxB = 0;
    hipError_t qerr = hipOccupancyMaxActiveBlocksPerMultiprocessor(
        &maxB, (const void*)fdtd_rt, 256, 0);
    bool done = false;
    if (qerr == hipSuccess && maxB >= 1) {   // 256 CUs x maxB >= 256 blocks
        hipLaunchKernelGGL(fdtd_zero_flags, dim3(4), dim3(256), 0, stream, flags);
        int t0b = 0, t0e = steps;
        void* args[] = { (void*)&in_out, (void*)&cmap, (void*)&locx,
                         (void*)&locy, (void*)&pb, (void*)&pid2, (void*)&outp,
                         (void*)&steps, (void*)&t0b, (void*)&t0e, (void*)&flags };
        done = (hipLaunchCooperativeKernel((const void*)fdtd_rt, dim3(256),
                                           dim3(256), args, 0, stream)
                == hipSuccess);
    }
    if (!done) {
        // fallback: same kernel, one group per plain launch (proven path)
        for (int g = 0; g < steps; g += TS) {
            int t0e1 = (g + TS < steps) ? (g + TS) : steps;
            hipLaunchKernelGGL(fdtd_rt, dim3(256), dim3(256), 0, stream,
                               in_out, cmap, locx, locy, pb, pid2, outp,
                               steps, g, t0e1, flags);
        }
    }
}

// Round 19
// 213.975 us; speedup vs baseline: 9.0319x; 9.0319x over previous
//
#include <hip/hip_runtime.h>

// FDTD rollout — SINGLE fused kernel (cooperative, flag-synced groups of
// TS=16; R10 structure) with an INSTRUCTION DIET (best verified: 216.8 us):
//  - steps unrolled in pairs, new frame written in place over prev (A/B role
//    swap, zero rotation movs)
//  - source sin values precomputed into an LDS table; consumed only by the
//    <=3 waves holding a source (uniform __any branch)
//  - row-0/row-511 boundary overrides reduced to two uniform bools
//    (geometry: only (by==0,w==2,j==0) and (by==15,w==5,j==7) qualify);
//    column overrides only in bx==0/15 blocks (template)
//  - pure interior wave step: 8 rows x (2 DPP + 6 VALU) + 4 LDS + 8 stores.

#define HH 512
#define WW 512
#define HW (HH * WW)
#define TILE 32
#define TS 16
#define NW 8      // waves per block
#define RPT 8     // rows per thread
#define PHC ((float)(2.0 * 3.1415926 * 100.0))

#define LDS_BARRIER() asm volatile("s_waitcnt lgkmcnt(0)\n\ts_barrier" ::: "memory")

#if __has_builtin(__builtin_amdgcn_update_dpp)
__device__ __forceinline__ float nbrL(float x) {   // value from lane-1 (left)
    int i = __builtin_bit_cast(int, x);
    i = __builtin_amdgcn_update_dpp(i, i, 0x138, 0xf, 0xf, false); // wave_shr:1
    return __builtin_bit_cast(float, i);
}
__device__ __forceinline__ float nbrR(float x) {   // value from lane+1 (right)
    int i = __builtin_bit_cast(int, x);
    i = __builtin_amdgcn_update_dpp(i, i, 0x130, 0xf, 0xf, false); // wave_shl:1
    return __builtin_bit_cast(float, i);
}
#else
__device__ __forceinline__ float nbrL(float x) { return __shfl_up(x, 1, 64); }
__device__ __forceinline__ float nbrR(float x) { return __shfl_down(x, 1, 64); }
#endif

__global__ void fdtd_zero_flags(int* f) { f[threadIdx.x] = 0; }

// One step: reads cur=X (+halo via sbR), prev=Y; writes new frame into Y.
template<bool COLEDGE>
__device__ __forceinline__ void fstep(
    float (&X)[RPT], float (&Y)[RPT],
    const float (&rr)[RPT], const float (&dcv)[RPT],
    const float (*sbR)[2][64], float (*sbW)[2][64],
    int lane, int w, int wup, int sup, int wdn, int sdn,
    bool topw, bool botw, bool isC0, bool isC511,
    bool whs, unsigned smask, const float (&srcT)[260], int n,
    bool keep, float* op)
{
    const float upb = sbR[wup][sup][lane];
    const float dnb = sbR[wdn][sdn][lane];
    #pragma unroll
    for (int j = 0; j < RPT; ++j) {
        const float c = X[j];
        const float u = (j == 0)       ? upb : X[j - 1];
        const float d = (j == RPT - 1) ? dnb : X[j + 1];
        const float lft = nbrL(c);
        const float rgt = nbrR(c);
        Y[j] = 2.f * c - Y[j] + rr[j] * (((u + d) + (lft + rgt)) - 4.f * c);
    }
    if (whs) {                       // only waves containing a source
        const float srcv = srcT[n];
        #pragma unroll
        for (int j = 0; j < RPT; ++j)
            if ((smask >> j) & 1u) Y[j] = srcv;
    }
    // precedence (last wins): row0 < col0 < col511 < row511
    if (topw) Y[0] = X[0] - dcv[0] * (X[0] - X[1]);
    if (COLEDGE) {
        #pragma unroll
        for (int j = 0; j < RPT; ++j) {
            const float c   = X[j];
            const float rgt = nbrR(c);
            const float lft = nbrL(c);
            float v = Y[j];
            v = isC0   ? (c - dcv[j] * (c - rgt)) : v;
            v = isC511 ? (c - dcv[j] * (c - lft)) : v;
            Y[j] = v;
        }
    }
    if (botw) Y[RPT - 1] = X[RPT - 1] - dcv[RPT - 1] * (X[RPT - 1] - X[RPT - 2]);
    sbW[w][0][lane] = Y[0];
    sbW[w][1][lane] = Y[RPT - 1];
    if (keep) {
        #pragma unroll
        for (int j = 0; j < RPT; ++j)
            __hip_atomic_store(op + j * WW, Y[j], __ATOMIC_RELAXED,
                               __HIP_MEMORY_SCOPE_AGENT);
    }
    LDS_BARRIER();
}

__global__ __launch_bounds__(512)
void fdtd_diet(const float* __restrict__ in_out,
               const float* __restrict__ cmap,
               const int* __restrict__ locx,
               const int* __restrict__ locy,
               const int* __restrict__ pb,
               const int* __restrict__ pid2,
               float* __restrict__ out,
               int steps, int* __restrict__ flags)
{
    __shared__ float sb[2][NW][2][64];   // [buf][wave][top/bottom row][col]
    __shared__ float srcT[260];          // source value per global step n

    const int tid  = threadIdx.x;
    const int lane = tid & 63;
    const int w    = tid >> 6;
    const int bx   = blockIdx.x & 15;
    const int by   = blockIdx.x >> 4;
    const int gx0  = bx * TILE - TS;
    const int gy0  = by * TILE - TS;
    const int gc   = gx0 + lane;
    const int R    = w * RPT;

    const int lx0 = locx[0], ly0 = locy[0];
    const int lx1 = locx[1], ly1 = locy[1];
    const int lx2 = locx[2], ly2 = locy[2];
    const int Bn  = pb[0] * pid2[0];

    if (tid <= steps && tid < 260)
        srcT[tid] = 1500.0f * __sinf(PHC * (float)(Bn + tid + 1) * 1.0e-4f);

    float A[RPT], B[RPT], rr[RPT], dcv[RPT];
    unsigned smask = 0;
    const bool colOK = (gc >= 0) & (gc < WW);

    #pragma unroll
    for (int j = 0; j < RPT; ++j) {
        const int gr = gy0 + R + j;
        float c = 0.f, ce = 0.f, pp = 0.f;
        if (colOK && gr >= 0 && gr < HH) {
            const int gi = gr * WW + gc;
            c  = cmap[gi];
            ce = in_out[(size_t)HW + gi];  // frame 1 (cur)
            pp = in_out[gi];               // frame 0 (prev)
        }
        A[j] = ce; B[j] = pp;
        rr[j]  = 1.0e-8f * c * c;
        dcv[j] = 1.0e-4f * c;
        if ((gr == lx0 && gc == ly0) || (gr == lx1 && gc == ly1) ||
            (gr == lx2 && gc == ly2)) smask |= (1u << j);
    }
    const bool whs     = __any((int)(smask != 0));
    const bool topw    = (by == 0)  && (w == 2);   // owns global row 0 (j=0)
    const bool botw    = (by == 15) && (w == 5);   // owns global row 511 (j=7)
    const bool coledge = (bx == 0) || (bx == 15);
    const bool isC0    = (gc == 0);
    const bool isC511  = (gc == WW - 1);
    const bool keep    = (w >= 2) & (w <= 5) & (lane >= 16) & (lane < 48);
    const int  rowOff  = (gy0 + R) * WW + gc;

    const int wup = (w == 0)      ? 0      : w - 1;
    const int sup = (w == 0)      ? 0      : 1;
    const int wdn = (w == NW - 1) ? NW - 1 : w + 1;
    const int sdn = (w == NW - 1) ? 1      : 0;

    sb[0][w][0][lane] = A[0];
    sb[0][w][1][lane] = A[RPT - 1];
    __syncthreads();

    for (int t0 = 0; t0 < steps; t0 += TS) {
        const int nk = (steps - t0 < TS) ? (steps - t0) : TS;

        if (t0 > 0) {
            // ---- group boundary: inter-block neighbor-flag sync (R10) ----
            asm volatile("s_waitcnt vmcnt(0)" ::: "memory");
            __syncthreads();
            if (tid == 0)
                __hip_atomic_store(&flags[blockIdx.x], t0,
                                   __ATOMIC_RELAXED, __HIP_MEMORY_SCOPE_AGENT);
            if (tid < 8) {
                const int dy[8] = {-1,-1,-1, 0, 0, 1, 1, 1};
                const int dx[8] = {-1, 0, 1,-1, 1,-1, 0, 1};
                const int nby = by + dy[tid];
                const int nbx = bx + dx[tid];
                if (nby >= 0 && nby < 16 && nbx >= 0 && nbx < 16) {
                    const int nb = (nby << 4) | nbx;
                    while (__hip_atomic_load(&flags[nb], __ATOMIC_RELAXED,
                                             __HIP_MEMORY_SCOPE_AGENT) < t0)
                        __builtin_amdgcn_s_sleep(2);
                }
            }
            __syncthreads();
            if (!keep) {     // reload halo-ring threads' cur/prev
                const float* cF = out + (size_t)(t0 - 1) * (size_t)HW;
                const float* pF = cF - HW;
                #pragma unroll
                for (int j = 0; j < RPT; ++j) {
                    const int gr = gy0 + R + j;
                    float ce = 0.f, pp = 0.f;
                    if (colOK && gr >= 0 && gr < HH) {
                        const int gi = gr * WW + gc;
                        ce = __hip_atomic_load(cF + gi, __ATOMIC_RELAXED,
                                               __HIP_MEMORY_SCOPE_AGENT);
                        pp = __hip_atomic_load(pF + gi, __ATOMIC_RELAXED,
                                               __HIP_MEMORY_SCOPE_AGENT);
                    }
                    A[j] = ce; B[j] = pp;
                }
            }
            sb[0][w][0][lane] = A[0];
            sb[0][w][1][lane] = A[RPT - 1];
            __syncthreads();
        }

        float* op = out + (size_t)t0 * (size_t)HW + rowOff;
        if (!coledge) {
            for (int k = 1; k + 1 <= nk; k += 2) {
                fstep<false>(A, B, rr, dcv, sb[0], sb[1], lane, w, wup, sup,
                             wdn, sdn, topw, botw, isC0, isC511, whs, smask,
                             srcT, t0 + k, keep, op);
                op += HW;
                fstep<false>(B, A, rr, dcv, sb[1], sb[0], lane, w, wup, sup,
                             wdn, sdn, topw, botw, isC0, isC511, whs, smask,
                             srcT, t0 + k + 1, keep, op);
                op += HW;
            }
            if (nk & 1) {
                fstep<false>(A, B, rr, dcv, sb[0], sb[1], lane, w, wup, sup,
                             wdn, sdn, topw, botw, isC0, isC511, whs, smask,
                             srcT, t0 + nk, keep, op);
                #pragma unroll
                for (int j = 0; j < RPT; ++j) {
                    const float t = A[j]; A[j] = B[j]; B[j] = t;
                }
            }
        } else {
            for (int k = 1; k + 1 <= nk; k += 2) {
                fstep<true>(A, B, rr, dcv, sb[0], sb[1], lane, w, wup, sup,
                            wdn, sdn, topw, botw, isC0, isC511, whs, smask,
                            srcT, t0 + k, keep, op);
                op += HW;
                fstep<true>(B, A, rr, dcv, sb[1], sb[0], lane, w, wup, sup,
                            wdn, sdn, topw, botw, isC0, isC511, whs, smask,
                            srcT, t0 + k + 1, keep, op);
                op += HW;
            }
            if (nk & 1) {
                fstep<true>(A, B, rr, dcv, sb[0], sb[1], lane, w, wup, sup,
                            wdn, sdn, topw, botw, isC0, isC511, whs, smask,
                            srcT, t0 + nk, keep, op);
                #pragma unroll
                for (int j = 0; j < RPT; ++j) {
                    const float t = A[j]; A[j] = B[j]; B[j] = t;
                }
            }
        }
    }
}

extern "C" void kernel_launch(void* const* d_in, const int* in_sizes, int n_in,
                              void* d_out, int out_size, void* d_ws, size_t ws_size,
                              hipStream_t stream) {
    const float* in_out = (const float*)d_in[0];   // [steps+2, 1, 512, 512]
    const float* cmap   = (const float*)d_in[1];   // [1,1,512,512]
    const int*   locx   = (const int*)d_in[2];
    const int*   locy   = (const int*)d_in[3];
    const int*   pb     = (const int*)d_in[4];     // bsize1
    const int*   pid2   = (const int*)d_in[5];     // id2
    float*       outp   = (float*)d_out;
    int*         flags  = (int*)d_ws;              // 256 progress flags

    int steps = out_size / HW;

    hipLaunchKernelGGL(fdtd_zero_flags, dim3(1), dim3(256), 0, stream, flags);

    void* args[] = { (void*)&in_out, (void*)&cmap, (void*)&locx, (void*)&locy,
                     (void*)&pb, (void*)&pid2, (void*)&outp, (void*)&steps,
                     (void*)&flags };
    hipLaunchCooperativeKernel((const void*)fdtd_diet,
                               dim3((HH / TILE) * (WW / TILE)),  // 256 blocks
                               dim3(512), args, 0, stream);
}